// Round 10
// baseline (192.529 us; speedup 1.0000x reference)
//
#include <hip/hip_runtime.h>
#include <math.h>

#define B_    4
#define N_    16384
#define S_    1024
#define C1_   128
#define C2_   256
#define CIN_  384
#define H1_   256
#define H2_   128
#define BN_EPS_     1e-5f
#define INTERP_EPS_ 1e-8f

typedef _Float16 f16;
typedef _Float16 f16x4 __attribute__((ext_vector_type(4)));
typedef _Float16 f16x8 __attribute__((ext_vector_type(8)));
typedef float    f32x4 __attribute__((ext_vector_type(4)));
typedef unsigned int u32;

// async global->LDS, 16B per lane; LDS dest = wave-uniform base + lane*16
#define GLD16(g, l) \
  __builtin_amdgcn_global_load_lds((const __attribute__((address_space(1))) void*)(g), \
                                   (__attribute__((address_space(3))) void*)(l), 16, 0, 0)

// ---- ws layout (bytes); total 68.42 MB (proven size) ----
#define WS_IDXP 0            // u32 [65536] packed (i0 | i1<<10 | i2<<20)
#define WS_W    262144       // f32 [65536][3]
#define WS_XI   1048576      // f16 [65536][256] interpolated features
#define WS_H    34603008     // f16 [65536][256] hidden
#define WS_W1F  68157440     // f16 [256][384]
#define WS_W2F  68354048     // f16 [128][256]
#define WS_SC1  68419584
#define WS_SH1  68420608
#define WS_SC2  68421632
#define WS_SH2  68422144

// ---------------------------------------------------------------------------
// prep: w1,w2 -> f16; fold BN into (scale, shift)
// ---------------------------------------------------------------------------
__global__ __launch_bounds__(256) void prep_kernel(
    const float* __restrict__ w1, const float* __restrict__ w2,
    const float* __restrict__ g1, const float* __restrict__ b1,
    const float* __restrict__ m1, const float* __restrict__ v1,
    const float* __restrict__ g2, const float* __restrict__ b2,
    const float* __restrict__ m2, const float* __restrict__ v2,
    f16* __restrict__ w1f, f16* __restrict__ w2f,
    float* __restrict__ sc1, float* __restrict__ sh1,
    float* __restrict__ sc2, float* __restrict__ sh2)
{
    const int t = blockIdx.x * 256 + threadIdx.x;
    if (t < 98304) {
        w1f[t] = (f16)w1[t];
    } else if (t < 131072) {
        w2f[t - 98304] = (f16)w2[t - 98304];
    } else if (t < 131328) {
        const int c = t - 131072;
        const float s = g1[c] / sqrtf(v1[c] + BN_EPS_);
        sc1[c] = s; sh1[c] = b1[c] - m1[c] * s;
    } else if (t < 131456) {
        const int c = t - 131328;
        const float s = g2[c] / sqrtf(v2[c] + BN_EPS_);
        sc2[c] = s; sh2[c] = b2[c] - m2[c] * s;
    }
}

// ---------------------------------------------------------------------------
// topk (unchanged): branchless packed-key top-5 scan + f64 refine
// ---------------------------------------------------------------------------
__device__ __forceinline__ u32 umin_(u32 a, u32 b) { return a < b ? a : b; }
__device__ __forceinline__ u32 umax_(u32 a, u32 b) { return a > b ? a : b; }

#define KINS(k) do { \
    u32 c1 = umax_(s0, (k)); s0 = umin_(s0, (k)); \
    u32 c2 = umax_(s1, c1);  s1 = umin_(s1, c1);  \
    u32 c3 = umax_(s2, c2);  s2 = umin_(s2, c2);  \
    u32 c4 = umax_(s3, c3);  s3 = umin_(s3, c3);  \
    s4 = umin_(s4, c4); } while (0)

#define CSWAP(a_, b_) do { \
    if (rd[b_] < rd[a_] || (rd[b_] == rd[a_] && ri[b_] < ri[a_])) { \
      double td = rd[a_]; rd[a_] = rd[b_]; rd[b_] = td; \
      int ti = ri[a_]; ri[a_] = ri[b_]; ri[b_] = ti; } } while (0)

__global__ __launch_bounds__(256) void topk_kernel(
    const float* __restrict__ xyz1, const float* __restrict__ xyz2,
    u32* __restrict__ idxp_out, float* __restrict__ w_out)
{
    __shared__ float4 q[S_ + 8];
    const int b     = blockIdx.x >> 9;
    const int pbase = (blockIdx.x & 511) << 5;
    const int t     = threadIdx.x;

    for (int i = t; i < S_; i += 256) {
        const float* s = &xyz2[((size_t)b * S_ + i) * 3];
        float4 v; v.x = s[0]; v.y = s[1]; v.z = s[2]; v.w = 0.0f;
        q[i + (i >> 7)] = v;
    }
    __syncthreads();

    const int p     = pbase + (t >> 3);
    const int chunk = t & 7;
    const int qb    = chunk * 129;
    const int ebase = chunk << 7;
    const float* pp = &xyz1[((size_t)b * N_ + p) * 3];
    const float px = pp[0], py = pp[1], pz = pp[2];

    u32 s0 = 0xFFFFFFFFu, s1 = 0xFFFFFFFFu, s2 = 0xFFFFFFFFu,
        s3 = 0xFFFFFFFFu, s4 = 0xFFFFFFFFu;

    for (int i = 0; i < 128; i += 4) {
        #pragma unroll
        for (int u = 0; u < 4; ++u) {
            const float4 c = q[qb + i + u];
            const float dx = px - c.x, dy = py - c.y, dz = pz - c.z;
            const float dd = fmaf(dx, dx, fmaf(dy, dy, dz * dz));
            const u32 k = (__float_as_uint(dd) & 0xFFFFFC00u) | (u32)(ebase + i + u);
            KINS(k);
        }
    }

    #pragma unroll
    for (int msk = 1; msk <= 4; msk <<= 1) {
        u32 e0 = __shfl_xor(s0, msk), e1 = __shfl_xor(s1, msk);
        u32 e2 = __shfl_xor(s2, msk), e3 = __shfl_xor(s3, msk);
        u32 e4 = __shfl_xor(s4, msk);
        KINS(e0); KINS(e1); KINS(e2); KINS(e3); KINS(e4);
    }

    if (chunk == 0) {
        const double px6 = px, py6 = py, pz6 = pz;
        double rd[5]; int ri[5];
        const u32 ks[5] = {s0, s1, s2, s3, s4};
        #pragma unroll
        for (int j = 0; j < 5; ++j) {
            const int si = (int)(ks[j] & 1023u); ri[j] = si;
            const float4 c = q[si + (si >> 7)];
            const double dx = px6 - (double)c.x, dy = py6 - (double)c.y, dz = pz6 - (double)c.z;
            rd[j] = dx * dx + dy * dy + dz * dz;
        }
        CSWAP(0,1); CSWAP(1,2); CSWAP(0,1); CSWAP(2,3); CSWAP(1,2);
        CSWAP(0,1); CSWAP(3,4); CSWAP(2,3); CSWAP(1,2); CSWAP(0,1);
        const float r0 = 1.0f / ((float)rd[0] + INTERP_EPS_);
        const float r1 = 1.0f / ((float)rd[1] + INTERP_EPS_);
        const float r2 = 1.0f / ((float)rd[2] + INTERP_EPS_);
        const float rs = r0 + r1 + r2;
        const int row = b * N_ + p;
        idxp_out[row] = (u32)ri[0] | ((u32)ri[1] << 10) | ((u32)ri[2] << 20);
        w_out[row * 3 + 0] = r0 / rs;
        w_out[row * 3 + 1] = r1 / rs;
        w_out[row * 3 + 2] = r2 / rs;
    }
}

// ---------------------------------------------------------------------------
// interp (unchanged): 3-NN weighted gather -> xi f16 [65536][256], coalesced
// ---------------------------------------------------------------------------
__global__ __launch_bounds__(256) void interp_kernel(
    const float* __restrict__ points2, const u32* __restrict__ idxp,
    const float* __restrict__ wts, f16* __restrict__ xi)
{
    const int row  = blockIdx.x * 8 + (threadIdx.x >> 5);
    const int lane = threadIdx.x & 31;
    const int bb   = row >> 14;
    const u32 u    = idxp[row];
    const int i0 = (int)(u & 1023u), i1 = (int)((u >> 10) & 1023u), i2 = (int)(u >> 20);
    const float w0 = wts[row * 3], w1w = wts[row * 3 + 1], w2w = wts[row * 3 + 2];
    const float* p2b = points2 + (size_t)bb * S_ * C2_;
    const int c0 = lane * 8;

    const float4 a0 = *(const float4*)&p2b[i0 * C2_ + c0];
    const float4 a1 = *(const float4*)&p2b[i0 * C2_ + c0 + 4];
    const float4 b0 = *(const float4*)&p2b[i1 * C2_ + c0];
    const float4 b1 = *(const float4*)&p2b[i1 * C2_ + c0 + 4];
    const float4 d0 = *(const float4*)&p2b[i2 * C2_ + c0];
    const float4 d1 = *(const float4*)&p2b[i2 * C2_ + c0 + 4];

    f16x8 o;
    o[0] = (f16)fmaf(w0, a0.x, fmaf(w1w, b0.x, w2w * d0.x));
    o[1] = (f16)fmaf(w0, a0.y, fmaf(w1w, b0.y, w2w * d0.y));
    o[2] = (f16)fmaf(w0, a0.z, fmaf(w1w, b0.z, w2w * d0.z));
    o[3] = (f16)fmaf(w0, a0.w, fmaf(w1w, b0.w, w2w * d0.w));
    o[4] = (f16)fmaf(w0, a1.x, fmaf(w1w, b1.x, w2w * d1.x));
    o[5] = (f16)fmaf(w0, a1.y, fmaf(w1w, b1.y, w2w * d1.y));
    o[6] = (f16)fmaf(w0, a1.z, fmaf(w1w, b1.z, w2w * d1.z));
    o[7] = (f16)fmaf(w0, a1.w, fmaf(w1w, b1.w, w2w * d1.w));
    *(f16x8*)&xi[(size_t)row * C2_ + c0] = o;
}

// ---------------------------------------------------------------------------
// gemm1: GEMM 65536x384 @ w1^T + BN+ReLU -> h f16.
// 128x128 tile (grid 512x2), BK=32, 4 waves 2x2, wave tile 64x64, acc[4][4].
// 2-phase dbuf pipeline; 3 blocks/CU for latency hiding (was 2 @ 128x256).
// ---------------------------------------------------------------------------
__global__ __launch_bounds__(256, 3) void gemm1_kernel(
    const float* __restrict__ points1, const f16* __restrict__ xi,
    const f16* __restrict__ w1f,
    const float* __restrict__ sc1v, const float* __restrict__ sh1v,
    f16* __restrict__ h)
{
    __shared__ __align__(16) f16 As[2 * 128 * 32];   // 16 KB
    __shared__ __align__(16) f16 Bs[2 * 128 * 32];   // 16 KB

    const int t = threadIdx.x;
    const int w = t >> 6;
    const int lane = t & 63;
    const int wr = w >> 1, wc = w & 1;
    const int lrow = lane & 15, lhi = lane >> 4;
    const int rowbase = blockIdx.x * 128;
    const int colbase = blockIdx.y * 64 * 2;         // 128-col block

    const int srow = t >> 1, khalf = t & 1;
    const float* p1r = points1 + (size_t)(rowbase + srow) * C1_;

    f32x4 acc[4][4] = {};
    float4 pre0, pre1, pre2, pre3;

    // prologue: stage step 0 (kb=0, phase A) into buffer 0
    {
        const float* src = p1r + khalf * 16;
        pre0 = *(const float4*)(src + 0);
        pre1 = *(const float4*)(src + 4);
        pre2 = *(const float4*)(src + 8);
        pre3 = *(const float4*)(src + 12);
        f16* asrow = As + srow * 32 + khalf * 16;
        f16x4 o0 = {(f16)pre0.x, (f16)pre0.y, (f16)pre0.z, (f16)pre0.w};
        f16x4 o1 = {(f16)pre1.x, (f16)pre1.y, (f16)pre1.z, (f16)pre1.w};
        f16x4 o2 = {(f16)pre2.x, (f16)pre2.y, (f16)pre2.z, (f16)pre2.w};
        f16x4 o3 = {(f16)pre3.x, (f16)pre3.y, (f16)pre3.z, (f16)pre3.w};
        *(f16x4*)(asrow + 0) = o0; *(f16x4*)(asrow + 4) = o1;
        *(f16x4*)(asrow + 8) = o2; *(f16x4*)(asrow + 12) = o3;
        #pragma unroll
        for (int j = 0; j < 2; ++j) {
            const int c = j * 256 + t;
            GLD16(w1f + (size_t)(colbase + (c >> 2)) * CIN_ + (c & 3) * 8,
                  (char*)Bs + (j * 4096 + w * 1024));
        }
    }
    __syncthreads();

    for (int step = 0; step < 12; ++step) {
        const int pb = step & 1, nb = pb ^ 1;
        const int nkb = (step + 1) * 32;
        const bool has_next = (step < 11);
        const bool nextA = (nkb < C1_);

        if (has_next) {
            if (nextA) {
                const float* src = p1r + nkb + khalf * 16;
                pre0 = *(const float4*)(src + 0);
                pre1 = *(const float4*)(src + 4);
                pre2 = *(const float4*)(src + 8);
                pre3 = *(const float4*)(src + 12);
            } else {
                const int kk = nkb - C1_;
                #pragma unroll
                for (int j = 0; j < 2; ++j) {
                    const int c = j * 256 + t;
                    GLD16(xi + (size_t)(rowbase + (c >> 2)) * C2_ + kk + (c & 3) * 8,
                          (char*)As + (nb * 8192 + j * 4096 + w * 1024));
                }
            }
            #pragma unroll
            for (int j = 0; j < 2; ++j) {
                const int c = j * 256 + t;
                GLD16(w1f + (size_t)(colbase + (c >> 2)) * CIN_ + nkb + (c & 3) * 8,
                      (char*)Bs + (nb * 8192 + j * 4096 + w * 1024));
            }
        }

        {
            const f16* Ac = As + pb * 4096;
            const f16* Bc = Bs + pb * 4096;
            f16x8 af[4], bf[4];
            #pragma unroll
            for (int m = 0; m < 4; ++m)
                af[m] = *(const f16x8*)&Ac[(wr * 64 + m * 16 + lrow) * 32 + lhi * 8];
            #pragma unroll
            for (int n = 0; n < 4; ++n)
                bf[n] = *(const f16x8*)&Bc[(wc * 64 + n * 16 + lrow) * 32 + lhi * 8];
            #pragma unroll
            for (int m = 0; m < 4; ++m)
                #pragma unroll
                for (int n = 0; n < 4; ++n)
                    acc[m][n] = __builtin_amdgcn_mfma_f32_16x16x32_f16(af[m], bf[n], acc[m][n], 0, 0, 0);
        }

        if (has_next && nextA) {
            f16* asrow = As + nb * 4096 + srow * 32 + khalf * 16;
            f16x4 o0 = {(f16)pre0.x, (f16)pre0.y, (f16)pre0.z, (f16)pre0.w};
            f16x4 o1 = {(f16)pre1.x, (f16)pre1.y, (f16)pre1.z, (f16)pre1.w};
            f16x4 o2 = {(f16)pre2.x, (f16)pre2.y, (f16)pre2.z, (f16)pre2.w};
            f16x4 o3 = {(f16)pre3.x, (f16)pre3.y, (f16)pre3.z, (f16)pre3.w};
            *(f16x4*)(asrow + 0) = o0; *(f16x4*)(asrow + 4) = o1;
            *(f16x4*)(asrow + 8) = o2; *(f16x4*)(asrow + 12) = o3;
        }
        __syncthreads();
    }

    // epilogue: BN+ReLU, store f16
    #pragma unroll
    for (int n = 0; n < 4; ++n) {
        const int col = colbase + wc * 64 + n * 16 + lrow;
        const float sc = sc1v[col], sh = sh1v[col];
        #pragma unroll
        for (int m = 0; m < 4; ++m) {
            const int row0 = rowbase + wr * 64 + m * 16 + lhi * 4;
            #pragma unroll
            for (int i = 0; i < 4; ++i) {
                const float v = fmaxf(fmaf(acc[m][n][i], sc, sh), 0.0f);
                h[(size_t)(row0 + i) * H1_ + col] = (f16)v;
            }
        }
    }
}

// ---------------------------------------------------------------------------
// gemm2: 65536x256 @ w2^T + BN+ReLU -> out f32.
// 64x128 tile (grid 1024), BK=32, 4 waves 2x2, wave tile 32x64, acc[2][4].
// 2-phase dbuf pipeline; 4 blocks/CU.
// ---------------------------------------------------------------------------
__global__ __launch_bounds__(256, 4) void gemm2_kernel(
    const f16* __restrict__ hin, const f16* __restrict__ w2f,
    const float* __restrict__ sc2v, const float* __restrict__ sh2v,
    float* __restrict__ out)
{
    __shared__ __align__(16) f16 As[2 * 64 * 32];    // 8 KB
    __shared__ __align__(16) f16 Bs[2 * 128 * 32];   // 16 KB

    const int t = threadIdx.x;
    const int w = t >> 6;
    const int lane = t & 63;
    const int wr = w >> 1, wc = w & 1;
    const int lrow = lane & 15, lhi = lane >> 4;
    const int rowbase = blockIdx.x * 64;

    f32x4 acc[2][4] = {};

    // prologue: stage kb=0 into buffer 0
    {
        GLD16(hin + (size_t)(rowbase + (t >> 2)) * H1_ + (t & 3) * 8,
              (char*)As + (w * 1024));
        #pragma unroll
        for (int j = 0; j < 2; ++j) {
            const int c = j * 256 + t;
            GLD16(w2f + (size_t)(c >> 2) * H1_ + (c & 3) * 8,
                  (char*)Bs + (j * 4096 + w * 1024));
        }
    }
    __syncthreads();

    for (int step = 0; step < 8; ++step) {
        const int pb = step & 1, nb = pb ^ 1;
        const int nkb = (step + 1) * 32;

        if (step < 7) {
            GLD16(hin + (size_t)(rowbase + (t >> 2)) * H1_ + nkb + (t & 3) * 8,
                  (char*)As + (nb * 4096 + w * 1024));
            #pragma unroll
            for (int j = 0; j < 2; ++j) {
                const int c = j * 256 + t;
                GLD16(w2f + (size_t)(c >> 2) * H1_ + nkb + (c & 3) * 8,
                      (char*)Bs + (nb * 8192 + j * 4096 + w * 1024));
            }
        }

        const f16* Ac = As + pb * 2048;
        const f16* Bc = Bs + pb * 4096;
        f16x8 af[2], bf[4];
        #pragma unroll
        for (int m = 0; m < 2; ++m)
            af[m] = *(const f16x8*)&Ac[(wr * 32 + m * 16 + lrow) * 32 + lhi * 8];
        #pragma unroll
        for (int n = 0; n < 4; ++n)
            bf[n] = *(const f16x8*)&Bc[(wc * 64 + n * 16 + lrow) * 32 + lhi * 8];
        #pragma unroll
        for (int m = 0; m < 2; ++m)
            #pragma unroll
            for (int n = 0; n < 4; ++n)
                acc[m][n] = __builtin_amdgcn_mfma_f32_16x16x32_f16(af[m], bf[n], acc[m][n], 0, 0, 0);

        __syncthreads();
    }

    #pragma unroll
    for (int n = 0; n < 4; ++n) {
        const int col = wc * 64 + n * 16 + lrow;
        const float sc = sc2v[col], sh = sh2v[col];
        #pragma unroll
        for (int m = 0; m < 2; ++m) {
            const int row0 = rowbase + wr * 32 + m * 16 + lhi * 4;
            #pragma unroll
            for (int i = 0; i < 4; ++i) {
                out[(size_t)(row0 + i) * H2_ + col] = fmaxf(fmaf(acc[m][n][i], sc, sh), 0.0f);
            }
        }
    }
}

// ---------------------------------------------------------------------------
extern "C" void kernel_launch(void* const* d_in, const int* in_sizes, int n_in,
                              void* d_out, int out_size, void* d_ws, size_t ws_size,
                              hipStream_t stream) {
    const float* xyz1    = (const float*)d_in[0];
    const float* xyz2    = (const float*)d_in[1];
    const float* points1 = (const float*)d_in[2];
    const float* points2 = (const float*)d_in[3];
    const float* w1      = (const float*)d_in[4];
    const float* g1      = (const float*)d_in[5];
    const float* b1      = (const float*)d_in[6];
    const float* m1      = (const float*)d_in[7];
    const float* v1      = (const float*)d_in[8];
    const float* w2      = (const float*)d_in[9];
    const float* g2      = (const float*)d_in[10];
    const float* b2      = (const float*)d_in[11];
    const float* m2      = (const float*)d_in[12];
    const float* v2      = (const float*)d_in[13];
    float* out = (float*)d_out;

    char* ws = (char*)d_ws;
    u32*   idxp_ws = (u32*)(ws + WS_IDXP);
    float* w_ws    = (float*)(ws + WS_W);
    f16*   xi_ws   = (f16*)(ws + WS_XI);
    f16*   h_ws    = (f16*)(ws + WS_H);
    f16*   w1f     = (f16*)(ws + WS_W1F);
    f16*   w2f     = (f16*)(ws + WS_W2F);
    float* sc1     = (float*)(ws + WS_SC1);
    float* sh1     = (float*)(ws + WS_SH1);
    float* sc2     = (float*)(ws + WS_SC2);
    float* sh2     = (float*)(ws + WS_SH2);

    topk_kernel<<<dim3(B_ * (N_ / 32)), dim3(256), 0, stream>>>(xyz1, xyz2, idxp_ws, w_ws);
    prep_kernel<<<dim3(514), dim3(256), 0, stream>>>(w1, w2, g1, b1, m1, v1,
                                                     g2, b2, m2, v2,
                                                     w1f, w2f, sc1, sh1, sc2, sh2);
    interp_kernel<<<dim3(B_ * N_ / 8), dim3(256), 0, stream>>>(points2, idxp_ws, w_ws, xi_ws);
    gemm1_kernel<<<dim3(512, 2), dim3(256), 0, stream>>>(points1, xi_ws, w1f, sc1, sh1, h_ws);
    gemm2_kernel<<<dim3(1024), dim3(256), 0, stream>>>(h_ws, w2f, sc2, sh2, out);
}

// Round 11
// 183.915 us; speedup vs baseline: 1.0468x; 1.0468x over previous
//
#include <hip/hip_runtime.h>
#include <math.h>

#define B_    4
#define N_    16384
#define S_    1024
#define C1_   128
#define C2_   256
#define CIN_  384
#define H1_   256
#define H2_   128
#define BN_EPS_     1e-5f
#define INTERP_EPS_ 1e-8f

typedef _Float16 f16;
typedef _Float16 f16x4 __attribute__((ext_vector_type(4)));
typedef _Float16 f16x8 __attribute__((ext_vector_type(8)));
typedef float    f32x4 __attribute__((ext_vector_type(4)));
typedef unsigned int u32;

// async global->LDS, 16B per lane; LDS dest = wave-uniform base + lane*16
#define GLD16(g, l) \
  __builtin_amdgcn_global_load_lds((const __attribute__((address_space(1))) void*)(g), \
                                   (__attribute__((address_space(3))) void*)(l), 16, 0, 0)

// ---- ws layout (bytes) ----
#define WS_XI   1048576      // f16 [65536][256] interpolated features
#define WS_W1F  68157440     // f16 [256][384]
#define WS_W2F  68354048     // f16 [128][256]
#define WS_SC1  68419584
#define WS_SH1  68420608
#define WS_SC2  68421632
#define WS_SH2  68422144

// ---------------------------------------------------------------------------
// front: fused {topk (branchless packed-key top-5 + f64 refine), interp
// (3-NN gather -> xi f16), prep (w->f16, BN fold)}. Blocks 0..2047: 32 points
// each (topk then interp, idx/weights handed through LDS). Blocks >=2048: prep.
// ---------------------------------------------------------------------------
__device__ __forceinline__ u32 umin_(u32 a, u32 b) { return a < b ? a : b; }
__device__ __forceinline__ u32 umax_(u32 a, u32 b) { return a > b ? a : b; }

#define KINS(k) do { \
    u32 c1 = umax_(s0, (k)); s0 = umin_(s0, (k)); \
    u32 c2 = umax_(s1, c1);  s1 = umin_(s1, c1);  \
    u32 c3 = umax_(s2, c2);  s2 = umin_(s2, c2);  \
    u32 c4 = umax_(s3, c3);  s3 = umin_(s3, c3);  \
    s4 = umin_(s4, c4); } while (0)

#define CSWAP(a_, b_) do { \
    if (rd[b_] < rd[a_] || (rd[b_] == rd[a_] && ri[b_] < ri[a_])) { \
      double td = rd[a_]; rd[a_] = rd[b_]; rd[b_] = td; \
      int ti = ri[a_]; ri[a_] = ri[b_]; ri[b_] = ti; } } while (0)

__global__ __launch_bounds__(256) void front_kernel(
    const float* __restrict__ xyz1, const float* __restrict__ xyz2,
    const float* __restrict__ points2,
    const float* __restrict__ w1, const float* __restrict__ w2,
    const float* __restrict__ g1, const float* __restrict__ b1,
    const float* __restrict__ m1, const float* __restrict__ v1,
    const float* __restrict__ g2, const float* __restrict__ b2,
    const float* __restrict__ m2, const float* __restrict__ v2,
    f16* __restrict__ xi, f16* __restrict__ w1f, f16* __restrict__ w2f,
    float* __restrict__ sc1, float* __restrict__ sh1,
    float* __restrict__ sc2, float* __restrict__ sh2)
{
    const int bid = blockIdx.x;
    const int t   = threadIdx.x;

    if (bid >= 2048) {                    // ---- prep blocks ----
        const int tg = (bid - 2048) * 256 + t;
        if (tg < 98304) {
            w1f[tg] = (f16)w1[tg];
        } else if (tg < 131072) {
            w2f[tg - 98304] = (f16)w2[tg - 98304];
        } else if (tg < 131328) {
            const int c = tg - 131072;
            const float s = g1[c] / sqrtf(v1[c] + BN_EPS_);
            sc1[c] = s; sh1[c] = b1[c] - m1[c] * s;
        } else if (tg < 131456) {
            const int c = tg - 131328;
            const float s = g2[c] / sqrtf(v2[c] + BN_EPS_);
            sc2[c] = s; sh2[c] = b2[c] - m2[c] * s;
        }
        return;
    }

    __shared__ float4 q[S_ + 8];
    __shared__ int   idr[32][3];
    __shared__ float wtr[32][3];

    const int b     = bid >> 9;
    const int pbase = (bid & 511) << 5;

    for (int i = t; i < S_; i += 256) {
        const float* s = &xyz2[((size_t)b * S_ + i) * 3];
        float4 v; v.x = s[0]; v.y = s[1]; v.z = s[2]; v.w = 0.0f;
        q[i + (i >> 7)] = v;
    }
    __syncthreads();

    {   // ---- topk: 8 threads/point, 128 candidates each ----
        const int p     = pbase + (t >> 3);
        const int chunk = t & 7;
        const int qb    = chunk * 129;
        const int ebase = chunk << 7;
        const float* pp = &xyz1[((size_t)b * N_ + p) * 3];
        const float px = pp[0], py = pp[1], pz = pp[2];

        u32 s0 = 0xFFFFFFFFu, s1 = 0xFFFFFFFFu, s2 = 0xFFFFFFFFu,
            s3 = 0xFFFFFFFFu, s4 = 0xFFFFFFFFu;

        for (int i = 0; i < 128; i += 4) {
            #pragma unroll
            for (int u = 0; u < 4; ++u) {
                const float4 c = q[qb + i + u];
                const float dx = px - c.x, dy = py - c.y, dz = pz - c.z;
                const float dd = fmaf(dx, dx, fmaf(dy, dy, dz * dz));
                const u32 k = (__float_as_uint(dd) & 0xFFFFFC00u) | (u32)(ebase + i + u);
                KINS(k);
            }
        }
        #pragma unroll
        for (int msk = 1; msk <= 4; msk <<= 1) {
            u32 e0 = __shfl_xor(s0, msk), e1 = __shfl_xor(s1, msk);
            u32 e2 = __shfl_xor(s2, msk), e3 = __shfl_xor(s3, msk);
            u32 e4 = __shfl_xor(s4, msk);
            KINS(e0); KINS(e1); KINS(e2); KINS(e3); KINS(e4);
        }
        if (chunk == 0) {
            const double px6 = px, py6 = py, pz6 = pz;
            double rd[5]; int ri[5];
            const u32 ks[5] = {s0, s1, s2, s3, s4};
            #pragma unroll
            for (int j = 0; j < 5; ++j) {
                const int si = (int)(ks[j] & 1023u); ri[j] = si;
                const float4 c = q[si + (si >> 7)];
                const double dx = px6 - (double)c.x, dy = py6 - (double)c.y, dz = pz6 - (double)c.z;
                rd[j] = dx * dx + dy * dy + dz * dz;
            }
            CSWAP(0,1); CSWAP(1,2); CSWAP(0,1); CSWAP(2,3); CSWAP(1,2);
            CSWAP(0,1); CSWAP(3,4); CSWAP(2,3); CSWAP(1,2); CSWAP(0,1);
            const float r0 = 1.0f / ((float)rd[0] + INTERP_EPS_);
            const float r1 = 1.0f / ((float)rd[1] + INTERP_EPS_);
            const float r2 = 1.0f / ((float)rd[2] + INTERP_EPS_);
            const float rs = r0 + r1 + r2;
            const int r = t >> 3;
            idr[r][0] = ri[0]; idr[r][1] = ri[1]; idr[r][2] = ri[2];
            wtr[r][0] = r0 / rs; wtr[r][1] = r1 / rs; wtr[r][2] = r2 / rs;
        }
    }
    __syncthreads();

    {   // ---- interp: 32 rows x 8 lanes, 32 cols/lane ----
        const int r = t >> 3, j = t & 7;
        const int i0 = idr[r][0], i1 = idr[r][1], i2 = idr[r][2];
        const float w0 = wtr[r][0], w1w = wtr[r][1], w2w = wtr[r][2];
        const float* p2b = points2 + (size_t)b * S_ * C2_;
        const int c0 = j * 32;
        float a[32];
        #pragma unroll
        for (int g = 0; g < 8; ++g) {
            const float4 f = *(const float4*)&p2b[i0 * C2_ + c0 + g * 4];
            a[g*4+0] = w0 * f.x; a[g*4+1] = w0 * f.y; a[g*4+2] = w0 * f.z; a[g*4+3] = w0 * f.w;
        }
        #pragma unroll
        for (int g = 0; g < 8; ++g) {
            const float4 f = *(const float4*)&p2b[i1 * C2_ + c0 + g * 4];
            a[g*4+0] = fmaf(w1w, f.x, a[g*4+0]); a[g*4+1] = fmaf(w1w, f.y, a[g*4+1]);
            a[g*4+2] = fmaf(w1w, f.z, a[g*4+2]); a[g*4+3] = fmaf(w1w, f.w, a[g*4+3]);
        }
        #pragma unroll
        for (int g = 0; g < 8; ++g) {
            const float4 f = *(const float4*)&p2b[i2 * C2_ + c0 + g * 4];
            a[g*4+0] = fmaf(w2w, f.x, a[g*4+0]); a[g*4+1] = fmaf(w2w, f.y, a[g*4+1]);
            a[g*4+2] = fmaf(w2w, f.z, a[g*4+2]); a[g*4+3] = fmaf(w2w, f.w, a[g*4+3]);
        }
        const size_t grow = (size_t)(b * N_ + pbase + r);
        #pragma unroll
        for (int g8 = 0; g8 < 4; ++g8) {
            f16x8 o;
            #pragma unroll
            for (int e = 0; e < 8; ++e) o[e] = (f16)a[g8 * 8 + e];
            *(f16x8*)&xi[grow * C2_ + c0 + g8 * 8] = o;
        }
    }
}

// ---------------------------------------------------------------------------
// mlp: fused {gemm1 (65536x384 @ w1^T, BN+ReLU) -> h in LDS (XOR-swizzled),
// gemm2 (h @ w2^T, BN+ReLU) -> out}. 128-row block, full 256 h-cols computed
// per block -> gemm2 is block-local, no h HBM round-trip.
// LDS: phase1 As(16K)+Bs(32K); phase2 Bs2(16K)+Ht(64K); union 80 KB dynamic.
// ---------------------------------------------------------------------------
__device__ __forceinline__ void mfma_step1(const f16* As, const f16* Bs,
                                           f32x4 (&acc)[4][8],
                                           int wr, int wc, int lrow, int lhi)
{
    f16x8 af[4], bf[8];
    #pragma unroll
    for (int m = 0; m < 4; ++m)
        af[m] = *(const f16x8*)&As[(wr * 64 + m * 16 + lrow) * 32 + lhi * 8];
    #pragma unroll
    for (int n = 0; n < 8; ++n)
        bf[n] = *(const f16x8*)&Bs[(wc * 128 + n * 16 + lrow) * 32 + lhi * 8];
    #pragma unroll
    for (int m = 0; m < 4; ++m)
        #pragma unroll
        for (int n = 0; n < 8; ++n)
            acc[m][n] = __builtin_amdgcn_mfma_f32_16x16x32_f16(af[m], bf[n], acc[m][n], 0, 0, 0);
}

__global__ __launch_bounds__(256, 2) void mlp_kernel(
    const float* __restrict__ points1, const f16* __restrict__ xi,
    const f16* __restrict__ w1f, const f16* __restrict__ w2f,
    const float* __restrict__ sc1v, const float* __restrict__ sh1v,
    const float* __restrict__ sc2v, const float* __restrict__ sh2v,
    float* __restrict__ out)
{
    extern __shared__ __align__(16) char smem[];     // 81920 B
    f16* As = (f16*)smem;                            // phase1 dbuf 2x(128x32)
    f16* Bs = (f16*)(smem + 16384);                  // phase1 dbuf 2x(256x32)
    char* Ht = smem + 16384;                         // phase2 h [128][256] swizzled

    const int t = threadIdx.x;
    const int w = t >> 6;
    const int lane = t & 63;
    const int wr = w >> 1, wc = w & 1;
    const int lrow = lane & 15, lhi = lane >> 4;
    const int rowbase = blockIdx.x * 128;

    const int srow = t >> 1, khalf = t & 1;
    const float* p1r = points1 + (size_t)(rowbase + srow) * C1_;

    f32x4 acc[4][8] = {};
    float4 pre0, pre1, pre2, pre3;

    // ---- phase 1: h = relu(bn(x @ w1^T)) into registers ----
    {
        const float* src = p1r + khalf * 16;
        pre0 = *(const float4*)(src + 0);
        pre1 = *(const float4*)(src + 4);
        pre2 = *(const float4*)(src + 8);
        pre3 = *(const float4*)(src + 12);
        f16* asrow = As + srow * 32 + khalf * 16;
        f16x4 o0 = {(f16)pre0.x, (f16)pre0.y, (f16)pre0.z, (f16)pre0.w};
        f16x4 o1 = {(f16)pre1.x, (f16)pre1.y, (f16)pre1.z, (f16)pre1.w};
        f16x4 o2 = {(f16)pre2.x, (f16)pre2.y, (f16)pre2.z, (f16)pre2.w};
        f16x4 o3 = {(f16)pre3.x, (f16)pre3.y, (f16)pre3.z, (f16)pre3.w};
        *(f16x4*)(asrow + 0) = o0; *(f16x4*)(asrow + 4) = o1;
        *(f16x4*)(asrow + 8) = o2; *(f16x4*)(asrow + 12) = o3;
        #pragma unroll
        for (int j = 0; j < 4; ++j) {
            const int c = j * 256 + t;
            GLD16(w1f + (size_t)(c >> 2) * CIN_ + (c & 3) * 8,
                  (char*)Bs + (j * 4096 + w * 1024));
        }
    }
    __syncthreads();

    for (int step = 0; step < 12; ++step) {
        const int pb = step & 1, nb = pb ^ 1;
        const int nkb = (step + 1) * 32;
        const bool has_next = (step < 11);
        const bool nextA = (nkb < C1_);

        if (has_next) {
            if (nextA) {
                const float* src = p1r + nkb + khalf * 16;
                pre0 = *(const float4*)(src + 0);
                pre1 = *(const float4*)(src + 4);
                pre2 = *(const float4*)(src + 8);
                pre3 = *(const float4*)(src + 12);
            } else {
                const int kk = nkb - C1_;
                #pragma unroll
                for (int j = 0; j < 2; ++j) {
                    const int c = j * 256 + t;
                    GLD16(xi + (size_t)(rowbase + (c >> 2)) * C2_ + kk + (c & 3) * 8,
                          (char*)As + (nb * 8192 + j * 4096 + w * 1024));
                }
            }
            #pragma unroll
            for (int j = 0; j < 4; ++j) {
                const int c = j * 256 + t;
                GLD16(w1f + (size_t)(c >> 2) * CIN_ + nkb + (c & 3) * 8,
                      (char*)Bs + (nb * 16384 + j * 4096 + w * 1024));
            }
        }

        mfma_step1(As + pb * 4096, Bs + pb * 8192, acc, wr, wc, lrow, lhi);

        if (has_next && nextA) {
            f16* asrow = As + nb * 4096 + srow * 32 + khalf * 16;
            f16x4 o0 = {(f16)pre0.x, (f16)pre0.y, (f16)pre0.z, (f16)pre0.w};
            f16x4 o1 = {(f16)pre1.x, (f16)pre1.y, (f16)pre1.z, (f16)pre1.w};
            f16x4 o2 = {(f16)pre2.x, (f16)pre2.y, (f16)pre2.z, (f16)pre2.w};
            f16x4 o3 = {(f16)pre3.x, (f16)pre3.y, (f16)pre3.z, (f16)pre3.w};
            *(f16x4*)(asrow + 0) = o0; *(f16x4*)(asrow + 4) = o1;
            *(f16x4*)(asrow + 8) = o2; *(f16x4*)(asrow + 12) = o3;
        }
        __syncthreads();
    }
    // all waves synced; As/Bs regions now dead.

    // ---- transition: issue phase-2 prologue staging, then h -> LDS ----
    #pragma unroll
    for (int j = 0; j < 2; ++j) {                    // w2f kb=0 -> Bs2 buf0
        const int c = j * 256 + t;
        GLD16(w2f + (size_t)(c >> 2) * H1_ + (c & 3) * 8,
              smem + (j * 4096 + w * 1024));
    }
    // BN+ReLU epilogue of phase 1, written to swizzled LDS Ht [row][col]
    #pragma unroll
    for (int n = 0; n < 8; ++n) {
        const int col = wc * 128 + n * 16 + lrow;
        const float sc = sc1v[col], sh = sh1v[col];
        #pragma unroll
        for (int m = 0; m < 4; ++m) {
            #pragma unroll
            for (int i = 0; i < 4; ++i) {
                const int row = wr * 64 + m * 16 + lhi * 4 + i;
                const float v = fmaxf(fmaf(acc[m][n][i], sc, sh), 0.0f);
                const u32 byteoff = (u32)(row * 512 + col * 2) ^ ((u32)(row & 7) << 4);
                *(f16*)(Ht + byteoff) = (f16)v;
            }
        }
    }
    __syncthreads();

    // ---- phase 2: out = relu(bn(h @ w2^T)), 8 K-steps, dbuf w2 staging ----
    f32x4 acc2[4][4] = {};
    for (int step = 0; step < 8; ++step) {
        const int pb = step & 1, nb = pb ^ 1;
        const int nkb = (step + 1) * 32;
        if (step < 7) {
            #pragma unroll
            for (int j = 0; j < 2; ++j) {
                const int c = j * 256 + t;
                GLD16(w2f + (size_t)(c >> 2) * H1_ + nkb + (c & 3) * 8,
                      smem + (nb * 8192 + j * 4096 + w * 1024));
            }
        }
        f16x8 af[4], bf[4];
        #pragma unroll
        for (int m = 0; m < 4; ++m) {
            const int row = wr * 64 + m * 16 + lrow;
            const u32 byteoff = (u32)(row * 512 + (step * 32 + lhi * 8) * 2) ^ ((u32)(row & 7) << 4);
            af[m] = *(const f16x8*)(Ht + byteoff);
        }
        const f16* Bc = (const f16*)(smem + pb * 8192);
        #pragma unroll
        for (int n = 0; n < 4; ++n)
            bf[n] = *(const f16x8*)&Bc[(wc * 64 + n * 16 + lrow) * 32 + lhi * 8];
        #pragma unroll
        for (int m = 0; m < 4; ++m)
            #pragma unroll
            for (int n = 0; n < 4; ++n)
                acc2[m][n] = __builtin_amdgcn_mfma_f32_16x16x32_f16(af[m], bf[n], acc2[m][n], 0, 0, 0);
        __syncthreads();
    }

    // ---- epilogue: out f32 ----
    #pragma unroll
    for (int n = 0; n < 4; ++n) {
        const int col = wc * 64 + n * 16 + lrow;
        const float sc = sc2v[col], sh = sh2v[col];
        #pragma unroll
        for (int m = 0; m < 4; ++m) {
            const int row0 = rowbase + wr * 64 + m * 16 + lhi * 4;
            #pragma unroll
            for (int i = 0; i < 4; ++i) {
                out[(size_t)(row0 + i) * H2_ + col] = fmaxf(fmaf(acc2[m][n][i], sc, sh), 0.0f);
            }
        }
    }
}

// ---------------------------------------------------------------------------
extern "C" void kernel_launch(void* const* d_in, const int* in_sizes, int n_in,
                              void* d_out, int out_size, void* d_ws, size_t ws_size,
                              hipStream_t stream) {
    const float* xyz1    = (const float*)d_in[0];
    const float* xyz2    = (const float*)d_in[1];
    const float* points1 = (const float*)d_in[2];
    const float* points2 = (const float*)d_in[3];
    const float* w1      = (const float*)d_in[4];
    const float* g1      = (const float*)d_in[5];
    const float* b1      = (const float*)d_in[6];
    const float* m1      = (const float*)d_in[7];
    const float* v1      = (const float*)d_in[8];
    const float* w2      = (const float*)d_in[9];
    const float* g2      = (const float*)d_in[10];
    const float* b2      = (const float*)d_in[11];
    const float* m2      = (const float*)d_in[12];
    const float* v2      = (const float*)d_in[13];
    float* out = (float*)d_out;

    char* ws = (char*)d_ws;
    f16*   xi_ws = (f16*)(ws + WS_XI);
    f16*   w1f   = (f16*)(ws + WS_W1F);
    f16*   w2f   = (f16*)(ws + WS_W2F);
    float* sc1   = (float*)(ws + WS_SC1);
    float* sh1   = (float*)(ws + WS_SH1);
    float* sc2   = (float*)(ws + WS_SC2);
    float* sh2   = (float*)(ws + WS_SH2);

    front_kernel<<<dim3(2562), dim3(256), 0, stream>>>(
        xyz1, xyz2, points2, w1, w2, g1, b1, m1, v1, g2, b2, m2, v2,
        xi_ws, w1f, w2f, sc1, sh1, sc2, sh2);
    mlp_kernel<<<dim3(512), dim3(256), 81920, stream>>>(
        points1, xi_ws, w1f, w2f, sc1, sh1, sc2, sh2, out);
}